// Round 13
// baseline (67.048 us; speedup 1.0000x reference)
//
#include <hip/hip_runtime.h>
#include <stdint.h>

#define MDIM 4096
#define NDIM 1024
#define KDIM 512
#define TSTEPS 50
#define NCH 16            // 16 chunks of BK=32; all 3 split-products per chunk

typedef _Float16 half8 __attribute__((ext_vector_type(8)));
typedef float    f32x4 __attribute__((ext_vector_type(4)));

typedef const __attribute__((address_space(1))) void cgv_t;
typedef __attribute__((address_space(3))) void lv_t;

__device__ __forceinline__ void gload16(const void* g, void* s) {
    __builtin_amdgcn_global_load_lds((cgv_t*)g, (lv_t*)s, 16, 0, 0);
}

// Pre-kernel: split fp32 -> (f16, f16 residual*2048) for A and W^T into
// 32-row-band k-major chunk images: byte offset within an image =
//   (row>>5)*32768 + chunk*2048 + lg*512 + (row&31)*16
// (lg = k-lane-group of 8 k, chunk = 32 k). A wave stages one chunk image
// with 2 linear gload16 (1KB each); frag ds_reads hit the 8-words/bank b128
// floor (each 16-lane group reads 16 distinct 16B slots of its 512B strip).
__global__ __launch_bounds__(256) void split_kernel(
    const float* __restrict__ A, const float* __restrict__ W,
    char* __restrict__ A1, char* __restrict__ A2,
    char* __restrict__ B1, char* __restrict__ B2,
    float* __restrict__ tot)
{
    const int blk = blockIdx.x;
    if (blk < 1024) {               // A path: 262144 = 4096 rows x 16 c x 4 lg
        int idx = blk * 256 + threadIdx.x;
        if (idx < MDIM) tot[idx] = 0.0f;    // fused tot-zeroing
        int r = idx >> 6, q = idx & 63, c = q >> 2, lg = q & 3;
        const float* pA = A + (size_t)r * KDIM + c * 32 + lg * 8;
        float4 v0 = *(const float4*)pA;
        float4 v1 = *(const float4*)(pA + 4);
        float v[8] = {v0.x, v0.y, v0.z, v0.w, v1.x, v1.y, v1.z, v1.w};
        half8 h1, h2;
        #pragma unroll
        for (int e = 0; e < 8; ++e) {
            h1[e] = (_Float16)v[e];
            h2[e] = (_Float16)((v[e] - (float)h1[e]) * 2048.0f);
        }
        int off = (r >> 5) * 32768 + c * 2048 + lg * 512 + ((r & 31) << 4);
        *(half8*)(A1 + off) = h1;
        *(half8*)(A2 + off) = h2;
    } else {                        // W path: 65536 = 64 (c,lg) x 1024 n
        int idx = (blk - 1024) * 256 + threadIdx.x;
        int q = idx >> 10, n = idx & 1023, c = q >> 2, lg = q & 3;
        float v[8];
        #pragma unroll
        for (int e = 0; e < 8; ++e)
            v[e] = W[(size_t)(c * 32 + lg * 8 + e) * NDIM + n];
        half8 h1, h2;
        #pragma unroll
        for (int e = 0; e < 8; ++e) {
            h1[e] = (_Float16)v[e];
            h2[e] = (_Float16)((v[e] - (float)h1[e]) * 2048.0f);
        }
        int off = (n >> 5) * 32768 + c * 2048 + lg * 512 + ((n & 31) << 4);
        *(half8*)(B1 + off) = h1;
        *(half8*)(B2 + off) = h2;
    }
}

// 1-wave blocks, 32x32 tile, ZERO barriers: the wave self-orders via
// vmcnt (its own global_load_lds) and lgkmcnt (its own ds_reads).
// Per chunk: 8 gload16 -> 8 ds_read_b128 -> 12 MFMA
//   (acc_hi += a2s*b1 ; acc_hi += a1*b2s ; acc_lo += a1*b1; per-element
//    math bit-identical to R12 -> absmax stays 1.0).
// lgkmcnt(0) BEFORE re-staging the just-read buffer: DMA writes (vmcnt queue)
// are not ordered against in-flight ds_reads (lgkm queue) -> explicit guard.
// LDS 16KB/block -> 10 blocks/CU, free-running (no cross-wave skew).
__global__ __launch_bounds__(64) void snn_mfma_kernel(
    const char* __restrict__ A1, const char* __restrict__ A2,
    const char* __restrict__ B1, const char* __restrict__ B2,
    const float* __restrict__ bias, float* __restrict__ agg, float* __restrict__ tot)
{
    __shared__ __align__(16) unsigned char lds[2][8192]; // A1|A2|B1|B2 2KB each

    const int l  = threadIdx.x;
    const int li = l & 15;
    const int lg = l >> 4;

    // XCD swizzle (bijective, 4096 = 8 x 512): XCD x gets mb in [x*16,x*16+16)
    // x all nb -> per-XCD L2 slice: A 1MB + B 2MB (fits 4MB).
    const int swz = (blockIdx.x & 7) * 512 + (blockIdx.x >> 3);
    const int m0 = (swz >> 5) * 32;
    const int n0 = (swz & 31) * 32;

    const char* a1p = A1 + (m0 >> 5) * 32768 + l * 16;
    const char* a2p = A2 + (m0 >> 5) * 32768 + l * 16;
    const char* b1p = B1 + (n0 >> 5) * 32768 + l * 16;
    const char* b2p = B2 + (n0 >> 5) * 32768 + l * 16;

#define STAGE(buf, ch) do {                                                   \
    const int c_ = (ch) * 2048;                                               \
    unsigned char* lb_ = &lds[buf][0];                                        \
    gload16(a1p + c_,        lb_);                                            \
    gload16(a1p + c_ + 1024, lb_ + 1024);                                     \
    gload16(a2p + c_,        lb_ + 2048);                                     \
    gload16(a2p + c_ + 1024, lb_ + 3072);                                     \
    gload16(b1p + c_,        lb_ + 4096);                                     \
    gload16(b1p + c_ + 1024, lb_ + 5120);                                     \
    gload16(b2p + c_,        lb_ + 6144);                                     \
    gload16(b2p + c_ + 1024, lb_ + 7168);                                     \
} while (0)

    // loop-invariant frag byte offsets
    int aF[2], bF[2];
    #pragma unroll
    for (int i = 0; i < 2; ++i) {
        aF[i] = lg * 512 + ((i * 16 + li) << 4);
        bF[i] = lg * 512 + ((i * 16 + li) << 4);
    }

    f32x4 acc_lo[2][2], acc_hi[2][2];
    #pragma unroll
    for (int i = 0; i < 2; ++i)
        #pragma unroll
        for (int j = 0; j < 2; ++j) {
            acc_lo[i][j] = (f32x4){0.f, 0.f, 0.f, 0.f};
            acc_hi[i][j] = (f32x4){0.f, 0.f, 0.f, 0.f};
        }

    STAGE(0, 0);
    STAGE(1, 1);

    #pragma unroll 1
    for (int ch = 0; ch < NCH; ++ch) {
        if (ch < NCH - 1) asm volatile("s_waitcnt vmcnt(8)" ::: "memory");
        else              asm volatile("s_waitcnt vmcnt(0)" ::: "memory");
        const unsigned char* sb = lds[ch & 1];

        half8 af1[2], af2[2], bf1[2], bf2[2];
        #pragma unroll
        for (int i = 0; i < 2; ++i) {
            af1[i] = *(const half8*)(sb + aF[i]);
            af2[i] = *(const half8*)(sb + 2048 + aF[i]);
            bf1[i] = *(const half8*)(sb + 4096 + bF[i]);
            bf2[i] = *(const half8*)(sb + 6144 + bF[i]);
        }
        #pragma unroll
        for (int i = 0; i < 2; ++i)
            #pragma unroll
            for (int j = 0; j < 2; ++j)
                acc_hi[i][j] = __builtin_amdgcn_mfma_f32_16x16x32_f16(
                    af2[i], bf1[j], acc_hi[i][j], 0, 0, 0);
        #pragma unroll
        for (int i = 0; i < 2; ++i)
            #pragma unroll
            for (int j = 0; j < 2; ++j)
                acc_hi[i][j] = __builtin_amdgcn_mfma_f32_16x16x32_f16(
                    af1[i], bf2[j], acc_hi[i][j], 0, 0, 0);
        #pragma unroll
        for (int i = 0; i < 2; ++i)
            #pragma unroll
            for (int j = 0; j < 2; ++j)
                acc_lo[i][j] = __builtin_amdgcn_mfma_f32_16x16x32_f16(
                    af1[i], bf1[j], acc_lo[i][j], 0, 0, 0);

        if (ch + 2 < NCH) {
            // reads of buf (ch&1) must drain before DMA overwrites it:
            // vmcnt and lgkm queues are mutually unordered.
            asm volatile("s_waitcnt lgkmcnt(0)" ::: "memory");
            STAGE(ch & 1, ch + 2);
        }
    }

    float cb[2];
    #pragma unroll
    for (int j = 0; j < 2; ++j) cb[j] = bias[n0 + j * 16 + li];

    // LIF recurrence: both layers identical -> simulate once.
    // spk_t == reset_{t+1}; fold reset: mem = fma(beta, mem, sp ? c-1 : c)
    #pragma unroll
    for (int i = 0; i < 2; ++i) {
        int rsum[4] = {0, 0, 0, 0};
        #pragma unroll
        for (int j = 0; j < 2; ++j) {
            float c[4], c1[4], mem[4];
            int cnt[4];
            bool sp[4];
            #pragma unroll
            for (int r = 0; r < 4; ++r) {
                c[r]   = fmaf(acc_hi[i][j][r], 4.8828125e-4f, acc_lo[i][j][r])
                       + cb[j];
                c1[r]  = c[r] - 1.0f;
                mem[r] = 0.0f;
                cnt[r] = 0;
                sp[r]  = false;
            }
            #pragma unroll 1
            for (int tt = 0; tt < TSTEPS; ++tt) {
                #pragma unroll
                for (int r = 0; r < 4; ++r) {
                    mem[r] = fmaf(0.95f, mem[r], sp[r] ? c1[r] : c[r]);
                    sp[r]  = mem[r] > 1.0f;
                    cnt[r] += sp[r] ? 1 : 0;
                }
            }
            const int col = n0 + j * 16 + li;
            #pragma unroll
            for (int r = 0; r < 4; ++r) {
                const int row = m0 + i * 16 + lg * 4 + r;
                agg[(size_t)row * NDIM + col] = (float)cnt[r];
                rsum[r] += cnt[r];
            }
        }
        // tot: integer counts, exact in fp32, order-independent atomics
        #pragma unroll
        for (int r = 0; r < 4; ++r) {
            int s = rsum[r];
            s += __shfl_xor(s, 1);
            s += __shfl_xor(s, 2);
            s += __shfl_xor(s, 4);
            s += __shfl_xor(s, 8);
            if (li == 0)
                atomicAdd(&tot[m0 + i * 16 + lg * 4 + r], 2.0f * (float)s);
        }
        __builtin_amdgcn_sched_barrier(0);  // sequence i-blocks: cap liveness
    }
}

extern "C" void kernel_launch(void* const* d_in, const int* in_sizes, int n_in,
                              void* d_out, int out_size, void* d_ws, size_t ws_size,
                              hipStream_t stream) {
    const float* x = (const float*)d_in[0];
    const float* W = (const float*)d_in[1];
    const float* b = (const float*)d_in[2];
    float* agg = (float*)d_out;
    float* tot = agg + (size_t)MDIM * NDIM;

    char* ws = (char*)d_ws;           // needs ws_size >= 10 MB
    char* A1 = ws;                    // 4 MB
    char* A2 = ws + (4 << 20);        // 4 MB
    char* B1 = ws + (8 << 20);        // 1 MB
    char* B2 = ws + (9 << 20);        // 1 MB

    split_kernel<<<1024 + 256, 256, 0, stream>>>(x, W, A1, A2, B1, B2,
                                                 (float*)tot);
    snn_mfma_kernel<<<(MDIM / 32) * (NDIM / 32), 64, 0, stream>>>(
        A1, A2, B1, B2, b, agg, tot);
}

// Round 14
// 60.944 us; speedup vs baseline: 1.1001x; 1.1001x over previous
//
#include <hip/hip_runtime.h>
#include <stdint.h>

#define MDIM 4096
#define NDIM 1024
#define KDIM 512
#define TSTEPS 50
#define NCH 16            // 16 chunks of BK=32; all 3 split-products per chunk

typedef _Float16 half8 __attribute__((ext_vector_type(8)));
typedef float    f32x4 __attribute__((ext_vector_type(4)));

typedef const __attribute__((address_space(1))) void cgv_t;
typedef __attribute__((address_space(3))) void lv_t;

__device__ __forceinline__ void gload16(const void* g, void* s) {
    __builtin_amdgcn_global_load_lds((cgv_t*)g, (lv_t*)s, 16, 0, 0);
}

// Pre-kernel (unchanged from R13): split fp32 -> (f16, f16 residual*2048) for
// A and W^T into 32-row-band k-major chunk images: byte offset =
//   (row>>5)*32768 + chunk*2048 + lg*512 + (row&31)*16
__global__ __launch_bounds__(256) void split_kernel(
    const float* __restrict__ A, const float* __restrict__ W,
    char* __restrict__ A1, char* __restrict__ A2,
    char* __restrict__ B1, char* __restrict__ B2,
    float* __restrict__ tot)
{
    const int blk = blockIdx.x;
    if (blk < 1024) {               // A path: 262144 = 4096 rows x 16 c x 4 lg
        int idx = blk * 256 + threadIdx.x;
        if (idx < MDIM) tot[idx] = 0.0f;    // fused tot-zeroing
        int r = idx >> 6, q = idx & 63, c = q >> 2, lg = q & 3;
        const float* pA = A + (size_t)r * KDIM + c * 32 + lg * 8;
        float4 v0 = *(const float4*)pA;
        float4 v1 = *(const float4*)(pA + 4);
        float v[8] = {v0.x, v0.y, v0.z, v0.w, v1.x, v1.y, v1.z, v1.w};
        half8 h1, h2;
        #pragma unroll
        for (int e = 0; e < 8; ++e) {
            h1[e] = (_Float16)v[e];
            h2[e] = (_Float16)((v[e] - (float)h1[e]) * 2048.0f);
        }
        int off = (r >> 5) * 32768 + c * 2048 + lg * 512 + ((r & 31) << 4);
        *(half8*)(A1 + off) = h1;
        *(half8*)(A2 + off) = h2;
    } else {                        // W path: 65536 = 64 (c,lg) x 1024 n
        int idx = (blk - 1024) * 256 + threadIdx.x;
        int q = idx >> 10, n = idx & 1023, c = q >> 2, lg = q & 3;
        float v[8];
        #pragma unroll
        for (int e = 0; e < 8; ++e)
            v[e] = W[(size_t)(c * 32 + lg * 8 + e) * NDIM + n];
        half8 h1, h2;
        #pragma unroll
        for (int e = 0; e < 8; ++e) {
            h1[e] = (_Float16)v[e];
            h2[e] = (_Float16)((v[e] - (float)h1[e]) * 2048.0f);
        }
        int off = (n >> 5) * 32768 + c * 2048 + lg * 512 + ((n & 31) << 4);
        *(half8*)(B1 + off) = h1;
        *(half8*)(B2 + off) = h2;
    }
}

// 32x32 tile, 128 threads (2 waves), 10 blocks/CU (LDS 16KB). R12's proven
// sync: counted vmcnt(4) -> barrier -> compute -> barrier -> stage ch+2.
// Wave 0 stages A1|A2, wave 1 stages B1|B2 (4x 1KB gload16 each).
// Per chunk per wave: 6 ds_read_b128 + 6 MFMA
//   (acc_hi += a2s*b1 ; acc_hi += a1*b2s ; acc_lo += a1*b1)
// Per-element math bit-identical to R12/R13 -> absmax stays 1.0.
__global__ __launch_bounds__(128, 5) void snn_mfma_kernel(
    const char* __restrict__ A1, const char* __restrict__ A2,
    const char* __restrict__ B1, const char* __restrict__ B2,
    const float* __restrict__ bias, float* __restrict__ agg, float* __restrict__ tot)
{
    __shared__ __align__(16) unsigned char lds[2][8192]; // A1|A2|B1|B2 2KB each

    const int t  = threadIdx.x;
    const int l  = t & 63;
    const int w  = t >> 6;      // wave 0: A-stager, wave 1: B-stager
    const int li = l & 15;
    const int lg = l >> 4;

    // XCD swizzle (bijective, 4096 = 8 x 512): XCD x gets 16 mb bands x all nb
    // -> per-XCD L2 slice: A 1MB + B 2MB.
    const int swz = (blockIdx.x & 7) * 512 + (blockIdx.x >> 3);
    const int m0 = (swz >> 5) * 32;
    const int n0 = (swz & 31) * 32;

    const char* a1p = A1 + (m0 >> 5) * 32768 + l * 16;
    const char* a2p = A2 + (m0 >> 5) * 32768 + l * 16;
    const char* b1p = B1 + (n0 >> 5) * 32768 + l * 16;
    const char* b2p = B2 + (n0 >> 5) * 32768 + l * 16;

#define STAGE(buf, ch) do {                                                   \
    const int c_ = (ch) * 2048;                                               \
    unsigned char* lb_ = &lds[buf][0];                                        \
    if (w == 0) {                                                             \
        gload16(a1p + c_,        lb_);                                        \
        gload16(a1p + c_ + 1024, lb_ + 1024);                                 \
        gload16(a2p + c_,        lb_ + 2048);                                 \
        gload16(a2p + c_ + 1024, lb_ + 3072);                                 \
    } else {                                                                  \
        gload16(b1p + c_,        lb_ + 4096);                                 \
        gload16(b1p + c_ + 1024, lb_ + 5120);                                 \
        gload16(b2p + c_,        lb_ + 6144);                                 \
        gload16(b2p + c_ + 1024, lb_ + 7168);                                 \
    }                                                                         \
} while (0)

    // loop-invariant frag byte offsets
    int aF[2];
    #pragma unroll
    for (int i = 0; i < 2; ++i) aF[i] = lg * 512 + ((i * 16 + li) << 4);
    const int bFo = 4096 + lg * 512 + ((w * 16 + li) << 4);

    f32x4 acc_lo[2], acc_hi[2];
    #pragma unroll
    for (int i = 0; i < 2; ++i) {
        acc_lo[i] = (f32x4){0.f, 0.f, 0.f, 0.f};
        acc_hi[i] = (f32x4){0.f, 0.f, 0.f, 0.f};
    }

    STAGE(0, 0);
    STAGE(1, 1);

    #pragma unroll 1
    for (int ch = 0; ch < NCH; ++ch) {
        if (ch < NCH - 1) asm volatile("s_waitcnt vmcnt(4)" ::: "memory");
        else              asm volatile("s_waitcnt vmcnt(0)" ::: "memory");
        __builtin_amdgcn_s_barrier();
        asm volatile("" ::: "memory");
        const unsigned char* sb = lds[ch & 1];

        half8 af1[2], af2[2], bf1, bf2;
        #pragma unroll
        for (int i = 0; i < 2; ++i) {
            af1[i] = *(const half8*)(sb + aF[i]);
            af2[i] = *(const half8*)(sb + 2048 + aF[i]);
        }
        bf1 = *(const half8*)(sb + bFo);
        bf2 = *(const half8*)(sb + 2048 + bFo);

        #pragma unroll
        for (int i = 0; i < 2; ++i)
            acc_hi[i] = __builtin_amdgcn_mfma_f32_16x16x32_f16(
                af2[i], bf1, acc_hi[i], 0, 0, 0);
        #pragma unroll
        for (int i = 0; i < 2; ++i)
            acc_hi[i] = __builtin_amdgcn_mfma_f32_16x16x32_f16(
                af1[i], bf2, acc_hi[i], 0, 0, 0);
        #pragma unroll
        for (int i = 0; i < 2; ++i)
            acc_lo[i] = __builtin_amdgcn_mfma_f32_16x16x32_f16(
                af1[i], bf1, acc_lo[i], 0, 0, 0);

        __builtin_amdgcn_s_barrier();
        asm volatile("" ::: "memory");
        if (ch + 2 < NCH) STAGE(ch & 1, ch + 2);
    }

    const float cb = bias[n0 + w * 16 + li];
    const int col = n0 + w * 16 + li;

    // LIF recurrence: both layers identical -> simulate once.
    // spk_t == reset_{t+1}; fold reset: mem = fma(beta, mem, sp ? c-1 : c)
    #pragma unroll
    for (int i = 0; i < 2; ++i) {
        float c[4], c1[4], mem[4];
        int cnt[4];
        bool sp[4];
        #pragma unroll
        for (int r = 0; r < 4; ++r) {
            c[r]   = fmaf(acc_hi[i][r], 4.8828125e-4f, acc_lo[i][r]) + cb;
            c1[r]  = c[r] - 1.0f;
            mem[r] = 0.0f;
            cnt[r] = 0;
            sp[r]  = false;
        }
        #pragma unroll 1
        for (int tt = 0; tt < TSTEPS; ++tt) {
            #pragma unroll
            for (int r = 0; r < 4; ++r) {
                mem[r] = fmaf(0.95f, mem[r], sp[r] ? c1[r] : c[r]);
                sp[r]  = mem[r] > 1.0f;
                cnt[r] += sp[r] ? 1 : 0;
            }
        }
        #pragma unroll
        for (int r = 0; r < 4; ++r) {
            const int row = m0 + i * 16 + lg * 4 + r;
            agg[(size_t)row * NDIM + col] = (float)cnt[r];
        }
        // tot: integer counts, exact in fp32, order-independent atomics
        #pragma unroll
        for (int r = 0; r < 4; ++r) {
            int s = cnt[r];
            s += __shfl_xor(s, 1);
            s += __shfl_xor(s, 2);
            s += __shfl_xor(s, 4);
            s += __shfl_xor(s, 8);
            if (li == 0)
                atomicAdd(&tot[m0 + i * 16 + lg * 4 + r], 2.0f * (float)s);
        }
        __builtin_amdgcn_sched_barrier(0);  // sequence i-blocks: cap liveness
    }
}

extern "C" void kernel_launch(void* const* d_in, const int* in_sizes, int n_in,
                              void* d_out, int out_size, void* d_ws, size_t ws_size,
                              hipStream_t stream) {
    const float* x = (const float*)d_in[0];
    const float* W = (const float*)d_in[1];
    const float* b = (const float*)d_in[2];
    float* agg = (float*)d_out;
    float* tot = agg + (size_t)MDIM * NDIM;

    char* ws = (char*)d_ws;           // needs ws_size >= 10 MB
    char* A1 = ws;                    // 4 MB
    char* A2 = ws + (4 << 20);        // 4 MB
    char* B1 = ws + (8 << 20);        // 1 MB
    char* B2 = ws + (9 << 20);        // 1 MB

    split_kernel<<<1024 + 256, 256, 0, stream>>>(x, W, A1, A2, B1, B2,
                                                 (float*)tot);
    snn_mfma_kernel<<<(MDIM / 32) * (NDIM / 32), 128, 0, stream>>>(
        A1, A2, B1, B2, b, agg, tot);
}

// Round 15
// 58.792 us; speedup vs baseline: 1.1404x; 1.0366x over previous
//
#include <hip/hip_runtime.h>
#include <stdint.h>

#define MDIM 4096
#define NDIM 1024
#define KDIM 512
#define TSTEPS 50
#define NCH 16            // 16 chunks of BK=32; all 3 split-products per chunk

typedef _Float16 half8 __attribute__((ext_vector_type(8)));
typedef float    f32x4 __attribute__((ext_vector_type(4)));

// Pre-kernel: split fp32 -> (f16, f16 residual*2048) for A and W^T into
// FRAG-SLOT images: for 16-row group g, chunk c, the 64 lanes of a wave read
// lane l -> (li=l&15 -> row g*16+li, lg=l>>4 -> k = c*32+lg*8..+8), stored at
//   byte off = (g*NCH + c)*1024 + (k8&3)*256 + (row&15)*16   [k8 = k/8]
// so one MFMA fragment = one coalesced 1KB global_load_dwordx4 at
// base + c*1024 + l*16. GEMM then needs NO LDS at all (images are L2-resident:
// ~3MB per XCD slice with the swizzle below).
__global__ __launch_bounds__(256) void split_kernel(
    const float* __restrict__ A, const float* __restrict__ W,
    char* __restrict__ A1, char* __restrict__ A2,
    char* __restrict__ B1, char* __restrict__ B2,
    float* __restrict__ tot)
{
    const int blk = blockIdx.x;
    if (blk < 1024) {               // A path: 262144 = 4096 rows x 64 k8
        int idx = blk * 256 + threadIdx.x;
        if (idx < MDIM) tot[idx] = 0.0f;    // fused tot-zeroing
        int r = idx >> 6, q = idx & 63;     // q = k8 index
        const float* pA = A + (size_t)r * KDIM + q * 8;
        float4 v0 = *(const float4*)pA;
        float4 v1 = *(const float4*)(pA + 4);
        float v[8] = {v0.x, v0.y, v0.z, v0.w, v1.x, v1.y, v1.z, v1.w};
        half8 h1, h2;
        #pragma unroll
        for (int e = 0; e < 8; ++e) {
            h1[e] = (_Float16)v[e];
            h2[e] = (_Float16)((v[e] - (float)h1[e]) * 2048.0f);
        }
        int off = ((r >> 4) * NCH + (q >> 2)) * 1024 + (q & 3) * 256
                + (r & 15) * 16;
        *(half8*)(A1 + off) = h1;
        *(half8*)(A2 + off) = h2;
    } else {                        // W path: 65536 = 64 k8 x 1024 n
        int idx = (blk - 1024) * 256 + threadIdx.x;
        int q = idx >> 10, n = idx & 1023;
        float v[8];
        #pragma unroll
        for (int e = 0; e < 8; ++e)
            v[e] = W[(size_t)(q * 8 + e) * NDIM + n];
        half8 h1, h2;
        #pragma unroll
        for (int e = 0; e < 8; ++e) {
            h1[e] = (_Float16)v[e];
            h2[e] = (_Float16)((v[e] - (float)h1[e]) * 2048.0f);
        }
        int off = ((n >> 4) * NCH + (q >> 2)) * 1024 + (q & 3) * 256
                + (n & 15) * 16;
        *(half8*)(B1 + off) = h1;
        *(half8*)(B2 + off) = h2;
    }
}

// NO-LDS streaming MFMA GEMM + fused LIF. 64x64 tile, 256 thr = 4 waves in
// 2x2 quadrants (32x32/wave, R12 geometry). Per chunk per wave: 8 coalesced
// 1KB global loads (L2-hit) + 12 MFMA:
//   acc_hi += a2s*b1 ; acc_hi += a1*b2s ; acc_lo += a1*b1
// Zero barriers, zero LDS, zero DMA: R7's proven P/Q 2-deep register pipeline
// (named buffers, static indices); TLP = 12 waves/CU hides L2 latency.
// Per-element math bit-identical to R12 -> same absmax class.
__global__ __launch_bounds__(256, 3) void snn_mfma_kernel(
    const char* __restrict__ A1, const char* __restrict__ A2,
    const char* __restrict__ B1, const char* __restrict__ B2,
    const float* __restrict__ bias, float* __restrict__ agg, float* __restrict__ tot)
{
    const int t  = threadIdx.x;
    const int l  = t & 63;
    const int w  = t >> 6;
    const int li = l & 15;
    const int lg = l >> 4;
    const int qr = (w >> 1) * 32;   // wave quadrant
    const int qc = (w & 1) * 32;

    // XCD swizzle (bijective, 1024 = 8 x 128): per-XCD slice A 1MB + B 2MB
    const int swz = (blockIdx.x & 7) * 128 + (blockIdx.x >> 3);
    const int m0 = (swz >> 4) * 64;
    const int n0 = (swz & 15) * 64;

    // per-wave frag image base pointers (lane offset l*16 folded in)
    const char* pa1 = A1 + (size_t)(((m0 + qr) >> 4) * NCH) * 1024 + l * 16;
    const char* pa2 = A2 + (size_t)(((m0 + qr) >> 4) * NCH) * 1024 + l * 16;
    const char* pb1 = B1 + (size_t)(((n0 + qc) >> 4) * NCH) * 1024 + l * 16;
    const char* pb2 = B2 + (size_t)(((n0 + qc) >> 4) * NCH) * 1024 + l * 16;

#define LOADC(ch, Fa1, Fa2, Fb1, Fb2) do {                                    \
    _Pragma("unroll") for (int i_ = 0; i_ < 2; ++i_) {                        \
        Fa1[i_] = *(const half8*)(pa1 + (i_ * NCH + (ch)) * 1024);            \
        Fa2[i_] = *(const half8*)(pa2 + (i_ * NCH + (ch)) * 1024);            \
        Fb1[i_] = *(const half8*)(pb1 + (i_ * NCH + (ch)) * 1024);            \
        Fb2[i_] = *(const half8*)(pb2 + (i_ * NCH + (ch)) * 1024);            \
    }                                                                         \
} while (0)

#define FMAC(Fa1, Fa2, Fb1, Fb2) do {                                        \
    _Pragma("unroll") for (int i_ = 0; i_ < 2; ++i_)                          \
        _Pragma("unroll") for (int j_ = 0; j_ < 2; ++j_)                      \
            acc_hi[i_][j_] = __builtin_amdgcn_mfma_f32_16x16x32_f16(          \
                Fa2[i_], Fb1[j_], acc_hi[i_][j_], 0, 0, 0);                   \
    _Pragma("unroll") for (int i_ = 0; i_ < 2; ++i_)                          \
        _Pragma("unroll") for (int j_ = 0; j_ < 2; ++j_)                      \
            acc_hi[i_][j_] = __builtin_amdgcn_mfma_f32_16x16x32_f16(          \
                Fa1[i_], Fb2[j_], acc_hi[i_][j_], 0, 0, 0);                   \
    _Pragma("unroll") for (int i_ = 0; i_ < 2; ++i_)                          \
        _Pragma("unroll") for (int j_ = 0; j_ < 2; ++j_)                      \
            acc_lo[i_][j_] = __builtin_amdgcn_mfma_f32_16x16x32_f16(          \
                Fa1[i_], Fb1[j_], acc_lo[i_][j_], 0, 0, 0);                   \
} while (0)

    f32x4 acc_lo[2][2], acc_hi[2][2];
    #pragma unroll
    for (int i = 0; i < 2; ++i)
        #pragma unroll
        for (int j = 0; j < 2; ++j) {
            acc_lo[i][j] = (f32x4){0.f, 0.f, 0.f, 0.f};
            acc_hi[i][j] = (f32x4){0.f, 0.f, 0.f, 0.f};
        }

    half8 Pa1[2], Pa2[2], Pb1[2], Pb2[2];
    half8 Qa1[2], Qa2[2], Qb1[2], Qb2[2];

    LOADC(0, Pa1, Pa2, Pb1, Pb2);
    #pragma unroll 1
    for (int tt = 0; tt < 7; ++tt) {        // pairs (0,1)..(12,13); P holds 2tt
        const int c0 = 2 * tt;
        LOADC(c0 + 1, Qa1, Qa2, Qb1, Qb2);  // in flight during FMAC(P)
        FMAC(Pa1, Pa2, Pb1, Pb2);
        LOADC(c0 + 2, Pa1, Pa2, Pb1, Pb2);  // in flight during FMAC(Q)
        FMAC(Qa1, Qa2, Qb1, Qb2);
    }
    LOADC(15, Qa1, Qa2, Qb1, Qb2);          // tail pair (14,15)
    FMAC(Pa1, Pa2, Pb1, Pb2);
    FMAC(Qa1, Qa2, Qb1, Qb2);

    float cb[2];
    #pragma unroll
    for (int j = 0; j < 2; ++j) cb[j] = bias[n0 + qc + j * 16 + li];

    // LIF recurrence: both layers identical -> simulate once.
    // spk_t == reset_{t+1}; fold reset: mem = fma(beta, mem, sp ? c-1 : c)
    #pragma unroll
    for (int i = 0; i < 2; ++i) {
        int rsum[4] = {0, 0, 0, 0};
        #pragma unroll
        for (int j = 0; j < 2; ++j) {
            float c[4], c1[4], mem[4];
            int cnt[4];
            bool sp[4];
            #pragma unroll
            for (int r = 0; r < 4; ++r) {
                c[r]   = fmaf(acc_hi[i][j][r], 4.8828125e-4f, acc_lo[i][j][r])
                       + cb[j];
                c1[r]  = c[r] - 1.0f;
                mem[r] = 0.0f;
                cnt[r] = 0;
                sp[r]  = false;
            }
            #pragma unroll 1
            for (int tt = 0; tt < TSTEPS; ++tt) {
                #pragma unroll
                for (int r = 0; r < 4; ++r) {
                    mem[r] = fmaf(0.95f, mem[r], sp[r] ? c1[r] : c[r]);
                    sp[r]  = mem[r] > 1.0f;
                    cnt[r] += sp[r] ? 1 : 0;
                }
            }
            const int col = n0 + qc + j * 16 + li;
            #pragma unroll
            for (int r = 0; r < 4; ++r) {
                const int row = m0 + qr + i * 16 + lg * 4 + r;
                agg[(size_t)row * NDIM + col] = (float)cnt[r];
                rsum[r] += cnt[r];
            }
        }
        // tot: integer counts, exact in fp32, order-independent atomics
        #pragma unroll
        for (int r = 0; r < 4; ++r) {
            int s = rsum[r];
            s += __shfl_xor(s, 1);
            s += __shfl_xor(s, 2);
            s += __shfl_xor(s, 4);
            s += __shfl_xor(s, 8);
            if (li == 0)
                atomicAdd(&tot[m0 + qr + i * 16 + lg * 4 + r], 2.0f * (float)s);
        }
        __builtin_amdgcn_sched_barrier(0);  // sequence i-blocks: cap liveness
    }
}

extern "C" void kernel_launch(void* const* d_in, const int* in_sizes, int n_in,
                              void* d_out, int out_size, void* d_ws, size_t ws_size,
                              hipStream_t stream) {
    const float* x = (const float*)d_in[0];
    const float* W = (const float*)d_in[1];
    const float* b = (const float*)d_in[2];
    float* agg = (float*)d_out;
    float* tot = agg + (size_t)MDIM * NDIM;

    char* ws = (char*)d_ws;           // needs ws_size >= 10 MB
    char* A1 = ws;                    // 4 MB
    char* A2 = ws + (4 << 20);        // 4 MB
    char* B1 = ws + (8 << 20);        // 1 MB
    char* B2 = ws + (9 << 20);        // 1 MB

    split_kernel<<<1024 + 256, 256, 0, stream>>>(x, W, A1, A2, B1, B2,
                                                 (float*)tot);
    snn_mfma_kernel<<<(MDIM / 64) * (NDIM / 64), 256, 0, stream>>>(
        A1, A2, B1, B2, b, agg, tot);
}